// Round 4
// baseline (134.652 us; speedup 1.0000x reference)
//
#include <hip/hip_runtime.h>
#include <math.h>

#define OBS 8
#define ACT 4
#define DIN 12
#define NTRAIN 128
#define BATCH 8
#define NPAIR 36               // triangle a<=c
#define NPT (BATCH*NPAIR)      // 288 pair tasks
#define NGT (BATCH*OBS)        // 64 gp tasks
#define NTASK (NPT+NGT)        // 352
#define THREADS 512

// ws layout (floats)
#define WS_PM  0               // 64   pred_mean[b][e]
#define WS_CC  64              // 768  cross_cov[b][d][e]
#define WS_MN  832             // 512  main[b][a][c]
#define WS_TR  1344            // 64   trace[b][e]
#define WS_CNT 1408            // 1    completion counter (zeroed via memset node)

__device__ __forceinline__ float agload(const float* p) {
    return __hip_atomic_load(p, __ATOMIC_RELAXED, __HIP_MEMORY_SCOPE_AGENT);
}
__device__ __forceinline__ void agstore(float* p, float v) {
    __hip_atomic_store(p, v, __ATOMIC_RELAXED, __HIP_MEMORY_SCOPE_AGENT);
}

// ---------------------------------------------------------------------------
// One kernel: 352 blocks x 512 threads.
// Blocks 0..287: pair triangle (a<=c); 288..351: gp predictive.
// Each block: build 12x12, invert via 12-lane shuffle Gauss-Jordan (no
// spills, no barriers), sweep. Last block to finish runs the epilogue.
// ---------------------------------------------------------------------------
__global__ void __launch_bounds__(THREADS) k_all(
    const float* __restrict__ m_x, const float* __restrict__ s_x,
    const float* __restrict__ m_u, const float* __restrict__ s_u,
    const float* __restrict__ c_xu, const float* __restrict__ X,
    const float* __restrict__ ls, const float* __restrict__ vars,
    const float* __restrict__ noises, const float* __restrict__ beta,
    const float* __restrict__ invK, float* __restrict__ ws,
    float* __restrict__ out)
{
    int blk = blockIdx.x, tid = threadIdx.x;
    bool isPair = blk < NPT;
    int b, a = 0, c = 0, e = 0;
    if (isPair) {
        b = blk / NPAIR;
        int rem = blk % NPAIR;
        while (rem >= OBS - a) { rem -= OBS - a; a++; }
        c = a + rem;
    } else {
        int q = blk - NPT; b = q / OBS; e = q % OBS;
    }

    __shared__ float jvs[144];          // joint_var
    __shared__ float Wl[144];           // inverse
    __shared__ float mu[DIN];
    __shared__ float sc_wsum[DIN], sc_iA[DIN], sc_qc[DIN], sc_lam[DIN], sc_isum[DIN];
    __shared__ float s_cab;
    __shared__ __align__(16) float h[NTRAIN][12];
    __shared__ float basei[NTRAIN], wav[NTRAIN];
    __shared__ float red[8][13];
    __shared__ unsigned s_last;

    // ---- stage 0: joint_var + per-dim scalars ----
    if (tid < 144) {
        int r = tid / 12, cl = tid % 12;
        float v;
        if (r < OBS && cl < OBS) {
            v = s_x[(b*OBS+r)*OBS + cl];
        } else if (r < OBS) {
            v = 0.f;
            #pragma unroll
            for (int k = 0; k < OBS; k++)
                v += s_x[(b*OBS+r)*OBS+k] * c_xu[(b*OBS+k)*ACT + (cl-OBS)];
        } else if (cl < OBS) {
            v = 0.f;
            #pragma unroll
            for (int k = 0; k < OBS; k++)
                v += s_x[(b*OBS+cl)*OBS+k] * c_xu[(b*OBS+k)*ACT + (r-OBS)];
        } else {
            v = s_u[(b*ACT+r-OBS)*ACT + (cl-OBS)];
        }
        jvs[tid] = v;
    } else if (tid >= 160 && tid < 172) {
        int d = tid - 160;
        mu[d] = (d < OBS) ? m_x[b*OBS+d] : m_u[b*ACT+d-OBS];
    } else if (tid >= 192 && tid < 204) {
        int d = tid - 192;
        if (isPair) {
            float la = ls[a*DIN+d]; la *= la;
            float lc = ls[c*DIN+d]; lc *= lc;
            float ia = 1.f/la, ic = 1.f/lc;
            float is = ia + ic;
            float L  = 1.f/is;
            sc_wsum[d] = 1.f/(la+lc);
            sc_iA[d] = L*ia;       // r_i = iA*x_i - mu
            sc_qc[d] = L*ic;       // q_j = qc*x_j
            sc_lam[d] = L;
            sc_isum[d] = is;
        } else {
            sc_iA[d] = 1.f / ls[e*DIN+d];   // inv lengthscale
        }
    }
    __syncthreads();

    // ---- stage 1: 12-lane shuffle Gauss-Jordan (wave 0, lanes 0..11) ----
    if (tid < DIN) {
        int r = tid;
        float row[12];
        if (isPair) {
            #pragma unroll
            for (int j = 0; j < 12; j++) row[j] = jvs[r*12+j];
            row[r] += sc_lam[r];                       // M = jv + diag(Lam)
        } else {
            float ir = sc_iA[r];
            #pragma unroll
            for (int j = 0; j < 12; j++) row[j] = ir * sc_iA[j] * jvs[r*12+j];
            row[r] += 1.f;                             // B = il*jv*il + I
        }
        float det = 1.f;
        #pragma unroll
        for (int k = 0; k < 12; k++) {
            float p = __shfl(row[k], k);
            float ip = 1.f / p;
            det *= p;
            float prow[12];
            #pragma unroll
            for (int j = 0; j < 12; j++) prow[j] = __shfl(row[j], k) * ip;
            if (r == k) {
                #pragma unroll
                for (int j = 0; j < 12; j++) row[j] = prow[j];
                row[k] = ip;
            } else {
                float f = row[k];
                #pragma unroll
                for (int j = 0; j < 12; j++) if (j != k) row[j] -= f * prow[j];
                row[k] = -f * ip;
            }
        }
        #pragma unroll
        for (int j = 0; j < 12; j++) Wl[r*12+j] = row[j];
        if (r == 0) {
            if (isPair) {
                float s = det;                          // det(R)=det(M)*prod(isum)
                #pragma unroll
                for (int d = 0; d < 12; d++) s *= sc_isum[d];
                s_cab = vars[a]*vars[c] / sqrtf(s);
            } else {
                s_cab = vars[e] / sqrtf(det);
            }
        }
    }
    __syncthreads();

    // ---- stage 2: sweep ----
    if (isPair) {
        bool diag = (a == c);
        if (tid < NTRAIN) {
            int i = tid;
            const float4* xr = (const float4*)(X + i*DIN);
            float4 x0 = xr[0], x1 = xr[1], x2 = xr[2];
            float x[12] = {x0.x,x0.y,x0.z,x0.w, x1.x,x1.y,x1.z,x1.w, x2.x,x2.y,x2.z,x2.w};
            float r[12]; float e1 = 0.f;
            #pragma unroll
            for (int d = 0; d < 12; d++) {
                r[d] = sc_iA[d]*x[d] - mu[d];
                e1 += sc_wsum[d]*x[d]*x[d];
            }
            float alpha = 0.f;
            #pragma unroll
            for (int d = 0; d < 12; d++) {
                float u = 0.f;
                #pragma unroll
                for (int cl = 0; cl < 12; cl++) u += Wl[d*12+cl]*r[cl];
                alpha += r[d]*u;
                h[i][d] = sc_wsum[d]*x[d] - u*sc_qc[d];   // folded cross term
            }
            basei[i] = -0.5f*(e1 + alpha);
            wav[i] = beta[a*NTRAIN+i];
        }
        int j = tid & 127;
        float xj[12], basej, wc;
        {
            const float4* xr = (const float4*)(X + j*DIN);
            float4 x0 = xr[0], x1 = xr[1], x2 = xr[2];
            xj[0]=x0.x; xj[1]=x0.y; xj[2]=x0.z; xj[3]=x0.w;
            xj[4]=x1.x; xj[5]=x1.y; xj[6]=x1.z; xj[7]=x1.w;
            xj[8]=x2.x; xj[9]=x2.y; xj[10]=x2.z; xj[11]=x2.w;
            float q[12]; float e1 = 0.f;
            #pragma unroll
            for (int d = 0; d < 12; d++) {
                q[d] = sc_qc[d]*xj[d];
                e1 += sc_wsum[d]*xj[d]*xj[d];
            }
            float bq = 0.f;
            #pragma unroll
            for (int d = 0; d < 12; d++) {
                float u = 0.f;
                #pragma unroll
                for (int cl = 0; cl < 12; cl++) u += Wl[d*12+cl]*q[cl];
                bq += q[d]*u;
            }
            basej = -0.5f*(e1 + bq);
            wc = beta[c*NTRAIN+j];
        }
        __syncthreads();
        float accm = 0.f, acct = 0.f;
        const float* Ka = invK + a*NTRAIN*NTRAIN;
        int ip = tid >> 7;                           // 0..3, wave-uniform
        #pragma unroll 8
        for (int k = 0; k < 32; k++) {
            int i = ip + 4*k;                        // wave-uniform -> LDS broadcast
            const float4* hp = (const float4*)(&h[i][0]);
            float4 h0 = hp[0], h1 = hp[1], h2 = hp[2];
            float sA = fmaf(h0.x,xj[0], fmaf(h0.y,xj[1], fmaf(h0.z,xj[2], h0.w*xj[3])));
            float sB = fmaf(h1.x,xj[4], fmaf(h1.y,xj[5], fmaf(h1.z,xj[6], h1.w*xj[7])));
            float sC = fmaf(h2.x,xj[8], fmaf(h2.y,xj[9], fmaf(h2.z,xj[10], h2.w*xj[11])));
            float ev = __expf(sA + sB + sC + basei[i] + basej);
            accm = fmaf(wav[i], ev, accm);
            if (diag) acct = fmaf(Ka[i*NTRAIN+j], ev, acct);
        }
        accm *= wc;
        #pragma unroll
        for (int off = 32; off >= 1; off >>= 1) {
            accm += __shfl_xor(accm, off, 64);
            acct += __shfl_xor(acct, off, 64);
        }
        int wv = tid >> 6, lane = tid & 63;
        if (lane == 0) { red[wv][0] = accm; red[wv][1] = acct; }
        __syncthreads();
        if (tid == 0) {
            float m = 0.f, t = 0.f;
            #pragma unroll
            for (int w = 0; w < 8; w++) { m += red[w][0]; t += red[w][1]; }
            m *= s_cab; t *= s_cab;
            agstore(ws + WS_MN + b*64 + a*8 + c, m);
            agstore(ws + WS_MN + b*64 + c*8 + a, m);   // exact symmetry
            if (diag) agstore(ws + WS_TR + b*8 + a, t);
        }
    } else {
        // gp predictive path (threads 0..127 active)
        float vals[13];
        #pragma unroll
        for (int v = 0; v < 13; v++) vals[v] = 0.f;
        if (tid < NTRAIN) {
            int n = tid;
            const float4* xr = (const float4*)(X + n*DIN);
            float4 x0 = xr[0], x1 = xr[1], x2 = xr[2];
            float x[12] = {x0.x,x0.y,x0.z,x0.w, x1.x,x1.y,x1.z,x1.w, x2.x,x2.y,x2.z,x2.w};
            float iN[12];
            #pragma unroll
            for (int d = 0; d < 12; d++) iN[d] = (x[d]-mu[d]) * sc_iA[d];
            float qq = 0.f; float tv[12];
            #pragma unroll
            for (int d = 0; d < 12; d++) {
                float u = 0.f;
                #pragma unroll
                for (int cl = 0; cl < 12; cl++) u += Wl[d*12+cl]*iN[cl];
                tv[d] = u; qq += iN[d]*u;
            }
            float lb = __expf(-0.5f*qq) * beta[e*NTRAIN+n];
            vals[0] = lb;
            #pragma unroll
            for (int d = 0; d < 12; d++) vals[1+d] = tv[d]*sc_iA[d]*lb;
        }
        #pragma unroll
        for (int v = 0; v < 13; v++)
            #pragma unroll
            for (int off = 32; off >= 1; off >>= 1) vals[v] += __shfl_xor(vals[v], off, 64);
        int wv = tid >> 6, lane = tid & 63;
        if (lane == 0) {
            #pragma unroll
            for (int v = 0; v < 13; v++) red[wv][v] = vals[v];
        }
        __syncthreads();
        if (tid == 0) {
            float cn = s_cab;
            agstore(ws + WS_PM + b*OBS + e, cn*(red[0][0]+red[1][0]));
            for (int d = 0; d < 12; d++)
                agstore(ws + WS_CC + (b*DIN+d)*OBS + e, cn*(red[0][1+d]+red[1][1+d]));
        }
    }

    // ---- tail: last block to finish runs the epilogue ----
    __threadfence();
    if (tid == 0) {
        unsigned* cnt = (unsigned*)(ws + WS_CNT);
        unsigned old = __hip_atomic_fetch_add(cnt, 1u, __ATOMIC_ACQ_REL,
                                              __HIP_MEMORY_SCOPE_AGENT);
        s_last = (old == NTASK - 1) ? 1u : 0u;
    }
    __syncthreads();
    if (s_last) {
        __threadfence();
        int bb = tid >> 6, t = tid & 63;       // 8 batches x 64 threads
        int r = t >> 3, cl = t & 7;
        const float* pm = ws + WS_PM + bb*OBS;
        const float* cc = ws + WS_CC + bb*DIN*OBS;
        const float* mn = ws + WS_MN + bb*64;
        const float* tr = ws + WS_TR + bb*OBS;
        if (t < OBS)
            out[bb*OBS + t] = m_x[bb*OBS + t] + agload(pm + t);   // m_out
        float pmr = agload(pm + r), pmc = agload(pm + cl);
        float P = agload(mn + r*8 + cl);
        if (r == cl) P += vars[r] - agload(tr + r) + noises[r];
        P -= pmr * pmc;
        float sxr[8], sxc[8];
        #pragma unroll
        for (int d = 0; d < 8; d++) {
            sxr[d] = s_x[(bb*8+r)*8 + d];
            sxc[d] = s_x[(bb*8+cl)*8 + d];
        }
        float cxf = 0.f, cxfT = 0.f;
        #pragma unroll
        for (int d = 0; d < 8; d++) {
            cxf  += sxr[d] * agload(cc + d*8 + cl);
            cxfT += sxc[d] * agload(cc + d*8 + r);
        }
        #pragma unroll
        for (int d = 0; d < 4; d++) {
            float jr = 0.f, jc = 0.f;
            #pragma unroll
            for (int k = 0; k < 8; k++) {
                float cx = c_xu[(bb*OBS+k)*ACT + d];
                jr += sxr[k] * cx;
                jc += sxc[k] * cx;
            }
            cxf  += jr * agload(cc + (8+d)*8 + cl);
            cxfT += jc * agload(cc + (8+d)*8 + r);
        }
        float S = sxr[cl] + P + cxf + cxfT;
        if (r == cl) S += 1e-8f;
        out[64 + bb*64 + t] = S;                                   // s_out
    }
}

// ---------------------------------------------------------------------------
extern "C" void kernel_launch(void* const* d_in, const int* in_sizes, int n_in,
                              void* d_out, int out_size, void* d_ws, size_t ws_size,
                              hipStream_t stream) {
    const float* m_x    = (const float*)d_in[0];
    const float* s_x    = (const float*)d_in[1];
    const float* m_u    = (const float*)d_in[2];
    const float* s_u    = (const float*)d_in[3];
    const float* c_xu   = (const float*)d_in[4];
    const float* X      = (const float*)d_in[5];
    const float* ls     = (const float*)d_in[6];
    const float* vars   = (const float*)d_in[7];
    const float* noises = (const float*)d_in[8];
    const float* invK   = (const float*)d_in[9];
    const float* beta   = (const float*)d_in[10];
    float* out = (float*)d_out;
    float* ws  = (float*)d_ws;

    // zero the completion counter (graph-capturable async memset)
    hipMemsetAsync((char*)d_ws + WS_CNT*sizeof(float), 0, sizeof(unsigned), stream);
    k_all<<<NTASK, THREADS, 0, stream>>>(m_x, s_x, m_u, s_u, c_xu, X, ls, vars,
                                         noises, beta, invK, ws, out);
}

// Round 5
// 92.269 us; speedup vs baseline: 1.4593x; 1.4593x over previous
//
#include <hip/hip_runtime.h>
#include <math.h>

#define OBS 8
#define ACT 4
#define DIN 12
#define NTRAIN 128
#define BATCH 8
#define NPAIR 36               // triangle a<=c
#define NPT (BATCH*NPAIR)      // 288 pair tasks
#define NGT (BATCH*OBS)        // 64 gp tasks
#define NTASK (NPT+NGT)        // 352
#define HSTRIDE 68             // floats per h row (64B data + 16B pad, 16B-aligned)

// ws layout (floats)
#define WS_PM  0               // 64   pred_mean[b][e]
#define WS_CC  64              // 768  cross_cov[b][d][e]
#define WS_MN  832             // 512  main[b][a][c]
#define WS_TR  1344            // 64   trace[b][e]

// ---------------------------------------------------------------------------
// Main kernel: 352 blocks x 256 threads (4 waves).
// Blocks 0..287: pair triangle (a<=c); 288..351: gp predictive.
// Sweep: lane l owns j-columns {2l, 2l+1}; wave w sweeps i = w+4k.
// Per i: ONE packed 64B LDS row (4x ds_read_b128) feeds 128 entries.
// ---------------------------------------------------------------------------
__global__ void __launch_bounds__(256) k_fused(
    const float* __restrict__ m_x, const float* __restrict__ s_x,
    const float* __restrict__ m_u, const float* __restrict__ s_u,
    const float* __restrict__ c_xu, const float* __restrict__ X,
    const float* __restrict__ ls, const float* __restrict__ vars,
    const float* __restrict__ beta, const float* __restrict__ invK,
    float* __restrict__ ws)
{
    int blk = blockIdx.x, tid = threadIdx.x;
    int lane = tid & 63, w = tid >> 6;
    bool isPair = blk < NPT;
    int b, a = 0, c = 0, e = 0;
    if (isPair) {
        b = blk / NPAIR;
        int rem = blk % NPAIR;
        while (rem >= OBS - a) { rem -= OBS - a; a++; }
        c = a + rem;
    } else {
        int q = blk - NPT; b = q / OBS; e = q % OBS;
    }

    __shared__ float jvs[144];          // joint_var
    __shared__ float Wl[144];           // inverse
    __shared__ float mu[DIN];
    __shared__ float sc_wsum[DIN], sc_iA[DIN], sc_qc[DIN], sc_lam[DIN], sc_isum[DIN];
    __shared__ float s_cab;
    __shared__ __align__(16) float h[NTRAIN][HSTRIDE];  // {h0..h11, basei, wav, pad2}
    __shared__ float red[4][13];

    // ---- preload X rows into registers (overlaps with setup latency) ----
    int j0 = 2*lane;
    float xa[12], xb[12], xi[12];
    {
        const float4* xr = (const float4*)(X + j0*DIN);   // rows j0, j0+1 contiguous
        float4 t0 = xr[0], t1 = xr[1], t2 = xr[2], t3 = xr[3], t4 = xr[4], t5 = xr[5];
        xa[0]=t0.x; xa[1]=t0.y; xa[2]=t0.z; xa[3]=t0.w;
        xa[4]=t1.x; xa[5]=t1.y; xa[6]=t1.z; xa[7]=t1.w;
        xa[8]=t2.x; xa[9]=t2.y; xa[10]=t2.z; xa[11]=t2.w;
        xb[0]=t3.x; xb[1]=t3.y; xb[2]=t3.z; xb[3]=t3.w;
        xb[4]=t4.x; xb[5]=t4.y; xb[6]=t4.z; xb[7]=t4.w;
        xb[8]=t5.x; xb[9]=t5.y; xb[10]=t5.z; xb[11]=t5.w;
    }
    if (tid < NTRAIN) {
        const float4* xr = (const float4*)(X + tid*DIN);
        float4 t0 = xr[0], t1 = xr[1], t2 = xr[2];
        xi[0]=t0.x; xi[1]=t0.y; xi[2]=t0.z; xi[3]=t0.w;
        xi[4]=t1.x; xi[5]=t1.y; xi[6]=t1.z; xi[7]=t1.w;
        xi[8]=t2.x; xi[9]=t2.y; xi[10]=t2.z; xi[11]=t2.w;
    }

    // ---- stage 0: joint_var + per-dim scalars ----
    if (tid < 144) {
        int r = tid / 12, cl = tid % 12;
        float v;
        if (r < OBS && cl < OBS) {
            v = s_x[(b*OBS+r)*OBS + cl];
        } else if (r < OBS) {
            v = 0.f;
            #pragma unroll
            for (int k = 0; k < OBS; k++)
                v += s_x[(b*OBS+r)*OBS+k] * c_xu[(b*OBS+k)*ACT + (cl-OBS)];
        } else if (cl < OBS) {
            v = 0.f;
            #pragma unroll
            for (int k = 0; k < OBS; k++)
                v += s_x[(b*OBS+cl)*OBS+k] * c_xu[(b*OBS+k)*ACT + (r-OBS)];
        } else {
            v = s_u[(b*ACT+r-OBS)*ACT + (cl-OBS)];
        }
        jvs[tid] = v;
    } else if (tid >= 160 && tid < 172) {
        int d = tid - 160;
        mu[d] = (d < OBS) ? m_x[b*OBS+d] : m_u[b*ACT+d-OBS];
    } else if (tid >= 192 && tid < 204) {
        int d = tid - 192;
        if (isPair) {
            float la = ls[a*DIN+d]; la *= la;
            float lc = ls[c*DIN+d]; lc *= lc;
            float ia = 1.f/la, ic = 1.f/lc;
            float is = ia + ic;
            float L  = 1.f/is;
            sc_wsum[d] = 1.f/(la+lc);
            sc_iA[d] = L*ia;       // r_i = iA*x_i - mu
            sc_qc[d] = L*ic;       // q_j = qc*x_j
            sc_lam[d] = L;
            sc_isum[d] = is;
        } else {
            sc_iA[d] = 1.f / ls[e*DIN+d];   // inv lengthscale
        }
    }
    __syncthreads();

    // ---- stage 1: 12-lane shuffle Gauss-Jordan (wave 0, lanes 0..11) ----
    if (tid < DIN) {
        int r = tid;
        float row[12];
        if (isPair) {
            #pragma unroll
            for (int j = 0; j < 12; j++) row[j] = jvs[r*12+j];
            row[r] += sc_lam[r];                       // M = jv + diag(Lam)
        } else {
            float ir = sc_iA[r];
            #pragma unroll
            for (int j = 0; j < 12; j++) row[j] = ir * sc_iA[j] * jvs[r*12+j];
            row[r] += 1.f;                             // B = il*jv*il + I
        }
        float det = 1.f;
        #pragma unroll
        for (int k = 0; k < 12; k++) {
            float p = __shfl(row[k], k);
            float ip = 1.f / p;
            det *= p;
            float prow[12];
            #pragma unroll
            for (int j = 0; j < 12; j++) prow[j] = __shfl(row[j], k) * ip;
            if (r == k) {
                #pragma unroll
                for (int j = 0; j < 12; j++) row[j] = prow[j];
                row[k] = ip;
            } else {
                float f = row[k];
                #pragma unroll
                for (int j = 0; j < 12; j++) if (j != k) row[j] -= f * prow[j];
                row[k] = -f * ip;
            }
        }
        #pragma unroll
        for (int j = 0; j < 12; j++) Wl[r*12+j] = row[j];
        if (r == 0) {
            if (isPair) {
                float s = det;                          // det(R)=det(M)*prod(isum)
                #pragma unroll
                for (int d = 0; d < 12; d++) s *= sc_isum[d];
                s_cab = vars[a]*vars[c] / sqrtf(s);
            } else {
                s_cab = vars[e] / sqrtf(det);
            }
        }
    }
    __syncthreads();

    // ---- stage 2: sweep ----
    if (isPair) {
        bool diag = (a == c);
        if (tid < NTRAIN) {
            int i = tid;
            float r[12]; float e1 = 0.f;
            #pragma unroll
            for (int d = 0; d < 12; d++) {
                r[d] = sc_iA[d]*xi[d] - mu[d];
                e1 += sc_wsum[d]*xi[d]*xi[d];
            }
            float hrow[16];
            float alpha = 0.f;
            #pragma unroll
            for (int d = 0; d < 12; d++) {
                float u = 0.f;
                #pragma unroll
                for (int cl = 0; cl < 12; cl++) u += Wl[d*12+cl]*r[cl];
                alpha += r[d]*u;
                hrow[d] = sc_wsum[d]*xi[d] - u*sc_qc[d];   // folded cross term
            }
            hrow[12] = -0.5f*(e1 + alpha);                 // basei
            hrow[13] = beta[a*NTRAIN+i];                   // wav
            hrow[14] = 0.f; hrow[15] = 0.f;
            float4* hp = (float4*)&h[i][0];
            hp[0] = make_float4(hrow[0],hrow[1],hrow[2],hrow[3]);
            hp[1] = make_float4(hrow[4],hrow[5],hrow[6],hrow[7]);
            hp[2] = make_float4(hrow[8],hrow[9],hrow[10],hrow[11]);
            hp[3] = make_float4(hrow[12],hrow[13],hrow[14],hrow[15]);
        }
        // j-side: lane owns j0=2l, j1=2l+1 (both in registers)
        float basej0, basej1, wc0, wc1;
        {
            float q0[12], q1[12]; float e10 = 0.f, e11 = 0.f;
            #pragma unroll
            for (int d = 0; d < 12; d++) {
                q0[d] = sc_qc[d]*xa[d];
                q1[d] = sc_qc[d]*xb[d];
                e10 += sc_wsum[d]*xa[d]*xa[d];
                e11 += sc_wsum[d]*xb[d]*xb[d];
            }
            float bq0 = 0.f, bq1 = 0.f;
            #pragma unroll
            for (int d = 0; d < 12; d++) {
                float u0 = 0.f, u1 = 0.f;
                #pragma unroll
                for (int cl = 0; cl < 12; cl++) {
                    float wv = Wl[d*12+cl];
                    u0 += wv*q0[cl];
                    u1 += wv*q1[cl];
                }
                bq0 += q0[d]*u0;
                bq1 += q1[d]*u1;
            }
            basej0 = -0.5f*(e10 + bq0);
            basej1 = -0.5f*(e11 + bq1);
            wc0 = beta[c*NTRAIN + j0];
            wc1 = beta[c*NTRAIN + j0 + 1];
        }
        __syncthreads();
        float am0 = 0.f, am1 = 0.f, at0 = 0.f, at1 = 0.f;
        const float2* Kb = (const float2*)(invK + a*NTRAIN*NTRAIN);
        #pragma unroll 4
        for (int k = 0; k < 32; k++) {
            int i = w + 4*k;                         // wave-uniform -> LDS broadcast
            const float4* hp = (const float4*)&h[i][0];
            float4 h0 = hp[0], h1 = hp[1], h2 = hp[2], h3 = hp[3];
            float sA0 = fmaf(h0.x,xa[0], fmaf(h0.y,xa[1], fmaf(h0.z,xa[2], h0.w*xa[3])));
            float sB0 = fmaf(h1.x,xa[4], fmaf(h1.y,xa[5], fmaf(h1.z,xa[6], h1.w*xa[7])));
            float sC0 = fmaf(h2.x,xa[8], fmaf(h2.y,xa[9], fmaf(h2.z,xa[10], h2.w*xa[11])));
            float sA1 = fmaf(h0.x,xb[0], fmaf(h0.y,xb[1], fmaf(h0.z,xb[2], h0.w*xb[3])));
            float sB1 = fmaf(h1.x,xb[4], fmaf(h1.y,xb[5], fmaf(h1.z,xb[6], h1.w*xb[7])));
            float sC1 = fmaf(h2.x,xb[8], fmaf(h2.y,xb[9], fmaf(h2.z,xb[10], h2.w*xb[11])));
            float e0 = __expf(sA0 + sB0 + sC0 + h3.x + basej0);
            float e1v = __expf(sA1 + sB1 + sC1 + h3.x + basej1);
            am0 = fmaf(h3.y, e0, am0);
            am1 = fmaf(h3.y, e1v, am1);
            if (diag) {
                float2 kv = Kb[i*64 + lane];          // Ka[i][2l], Ka[i][2l+1]
                at0 = fmaf(kv.x, e0, at0);
                at1 = fmaf(kv.y, e1v, at1);
            }
        }
        float accm = am0*wc0 + am1*wc1;
        float acct = at0 + at1;
        #pragma unroll
        for (int off = 32; off >= 1; off >>= 1) {
            accm += __shfl_xor(accm, off, 64);
            acct += __shfl_xor(acct, off, 64);
        }
        if (lane == 0) { red[w][0] = accm; red[w][1] = acct; }
        __syncthreads();
        if (tid == 0) {
            float m = (red[0][0]+red[1][0]+red[2][0]+red[3][0]) * s_cab;
            ws[WS_MN + b*64 + a*8 + c] = m;
            ws[WS_MN + b*64 + c*8 + a] = m;          // exact symmetry
            if (diag)
                ws[WS_TR + b*8 + a] = (red[0][1]+red[1][1]+red[2][1]+red[3][1]) * s_cab;
        }
    } else {
        // gp predictive path (threads 0..127 active)
        float vals[13];
        #pragma unroll
        for (int v = 0; v < 13; v++) vals[v] = 0.f;
        if (tid < NTRAIN) {
            int n = tid;
            float iN[12];
            #pragma unroll
            for (int d = 0; d < 12; d++) iN[d] = (xi[d]-mu[d]) * sc_iA[d];
            float qq = 0.f; float tv[12];
            #pragma unroll
            for (int d = 0; d < 12; d++) {
                float u = 0.f;
                #pragma unroll
                for (int cl = 0; cl < 12; cl++) u += Wl[d*12+cl]*iN[cl];
                tv[d] = u; qq += iN[d]*u;
            }
            float lb = __expf(-0.5f*qq) * beta[e*NTRAIN+n];
            vals[0] = lb;
            #pragma unroll
            for (int d = 0; d < 12; d++) vals[1+d] = tv[d]*sc_iA[d]*lb;
        }
        #pragma unroll
        for (int v = 0; v < 13; v++)
            #pragma unroll
            for (int off = 32; off >= 1; off >>= 1) vals[v] += __shfl_xor(vals[v], off, 64);
        if (lane == 0) {
            #pragma unroll
            for (int v = 0; v < 13; v++) red[w][v] = vals[v];
        }
        __syncthreads();
        if (tid == 0) {
            float cn = s_cab;
            ws[WS_PM + b*OBS + e] = cn*(red[0][0]+red[1][0]);
            for (int d = 0; d < 12; d++)
                ws[WS_CC + (b*DIN+d)*OBS + e] = cn*(red[0][1+d]+red[1][1+d]);
        }
    }
}

// ---------------------------------------------------------------------------
// Epilogue. 8 blocks x 64 threads.
// ---------------------------------------------------------------------------
__global__ void k_final(const float* __restrict__ m_x, const float* __restrict__ s_x,
                        const float* __restrict__ c_xu, const float* __restrict__ vars,
                        const float* __restrict__ noises, const float* __restrict__ ws,
                        float* __restrict__ out) {
    int b = blockIdx.x, t = threadIdx.x;
    __shared__ float pm[OBS];
    __shared__ float sxs[64];
    const float* cc = ws + WS_CC + b*DIN*OBS;
    const float* mn = ws + WS_MN + b*64;
    const float* tr = ws + WS_TR + b*OBS;
    sxs[t] = s_x[b*64 + t];
    if (t < OBS) {
        float p = ws[WS_PM + b*OBS + t];
        pm[t] = p;
        out[b*OBS + t] = m_x[b*OBS + t] + p;        // m_out
    }
    __syncthreads();
    int r = t >> 3, cl = t & 7;
    float P = mn[r*8 + cl];
    if (r == cl) P += vars[r] - tr[r] + noises[r];
    P -= pm[r]*pm[cl];
    float cxf = 0.f, cxfT = 0.f;
    #pragma unroll
    for (int d = 0; d < 8; d++) {
        cxf  += sxs[r*8+d]  * cc[d*8+cl];
        cxfT += sxs[cl*8+d] * cc[d*8+r];
    }
    #pragma unroll
    for (int d = 0; d < 4; d++) {
        float jr = 0.f, jc = 0.f;
        #pragma unroll
        for (int k = 0; k < 8; k++) {
            float cx = c_xu[(b*OBS+k)*ACT + d];
            jr += sxs[r*8+k]  * cx;
            jc += sxs[cl*8+k] * cx;
        }
        cxf  += jr * cc[(8+d)*8 + cl];
        cxfT += jc * cc[(8+d)*8 + r];
    }
    float S = sxs[r*8+cl] + P + cxf + cxfT;
    if (r == cl) S += 1e-8f;
    out[64 + b*64 + t] = S;                          // s_out
}

// ---------------------------------------------------------------------------
extern "C" void kernel_launch(void* const* d_in, const int* in_sizes, int n_in,
                              void* d_out, int out_size, void* d_ws, size_t ws_size,
                              hipStream_t stream) {
    const float* m_x    = (const float*)d_in[0];
    const float* s_x    = (const float*)d_in[1];
    const float* m_u    = (const float*)d_in[2];
    const float* s_u    = (const float*)d_in[3];
    const float* c_xu   = (const float*)d_in[4];
    const float* X      = (const float*)d_in[5];
    const float* ls     = (const float*)d_in[6];
    const float* vars   = (const float*)d_in[7];
    const float* noises = (const float*)d_in[8];
    const float* invK   = (const float*)d_in[9];
    const float* beta   = (const float*)d_in[10];
    float* out = (float*)d_out;
    float* ws  = (float*)d_ws;

    k_fused<<<NTASK, 256, 0, stream>>>(m_x, s_x, m_u, s_u, c_xu, X, ls, vars,
                                       beta, invK, ws);
    k_final<<<BATCH, 64, 0, stream>>>(m_x, s_x, c_xu, vars, noises, ws, out);
}

// Round 6
// 91.460 us; speedup vs baseline: 1.4723x; 1.0089x over previous
//
#include <hip/hip_runtime.h>
#include <math.h>

#define OBS 8
#define ACT 4
#define DIN 12
#define NTRAIN 128
#define BATCH 8
#define NPAIR 36               // triangle a<=c
#define NPT (BATCH*NPAIR)      // 288 pair tasks
#define NGT (BATCH*OBS)        // 64 gp tasks
#define NTASK (NPT+NGT)        // 352
#define THREADS 512
#define HSTRIDE 16             // floats per h row (64B; 2-way write alias = free)

// ws layout (floats)
#define WS_PM  0               // 64   pred_mean[b][e]
#define WS_CC  64              // 768  cross_cov[b][d][e]
#define WS_MN  832             // 512  main[b][a][c]
#define WS_TR  1344            // 64   trace[b][e]

// ---------------------------------------------------------------------------
// Main kernel: 352 blocks x 512 threads (8 waves).
// Blocks 0..287: pair triangle (a<=c); 288..351: gp predictive.
// Thread t<128 computes BOTH h-row i=t and (basej,wc) for j=t (one Wl pass).
// Sweep: lane l owns j-columns {2l,2l+1}; wave w sweeps i = w+8k, k<16.
// Per i: 3x ds_read_b128 + 1x ds_read_b64 (broadcast) feeds 128 entries.
// ---------------------------------------------------------------------------
__global__ void __launch_bounds__(THREADS) k_fused(
    const float* __restrict__ m_x, const float* __restrict__ s_x,
    const float* __restrict__ m_u, const float* __restrict__ s_u,
    const float* __restrict__ c_xu, const float* __restrict__ X,
    const float* __restrict__ ls, const float* __restrict__ vars,
    const float* __restrict__ beta, const float* __restrict__ invK,
    float* __restrict__ ws)
{
    int blk = blockIdx.x, tid = threadIdx.x;
    int lane = tid & 63, w = tid >> 6;
    bool isPair = blk < NPT;
    int b, a = 0, c = 0, e = 0;
    if (isPair) {
        b = blk / NPAIR;
        int rem = blk % NPAIR;
        while (rem >= OBS - a) { rem -= OBS - a; a++; }
        c = a + rem;
    } else {
        int q = blk - NPT; b = q / OBS; e = q % OBS;
    }

    __shared__ float jvs[144];          // joint_var
    __shared__ float Wl[144];           // inverse
    __shared__ float mu[DIN];
    __shared__ float sc_wsum[DIN], sc_iA[DIN], sc_qc[DIN], sc_lam[DIN], sc_isum[DIN];
    __shared__ float s_cab;
    __shared__ __align__(16) float h[NTRAIN][HSTRIDE];  // {h0..h11, basei, wav, pad2}
    __shared__ __align__(16) float2 bw[NTRAIN];         // {basej, wc}
    __shared__ float red[8][13];

    // ---- preload X rows into registers (overlaps with setup latency) ----
    int j0 = 2*lane;
    float xa[12], xb[12], xi[12];
    {
        const float4* xr = (const float4*)(X + j0*DIN);   // rows j0, j0+1 contiguous
        float4 t0 = xr[0], t1 = xr[1], t2 = xr[2], t3 = xr[3], t4 = xr[4], t5 = xr[5];
        xa[0]=t0.x; xa[1]=t0.y; xa[2]=t0.z; xa[3]=t0.w;
        xa[4]=t1.x; xa[5]=t1.y; xa[6]=t1.z; xa[7]=t1.w;
        xa[8]=t2.x; xa[9]=t2.y; xa[10]=t2.z; xa[11]=t2.w;
        xb[0]=t3.x; xb[1]=t3.y; xb[2]=t3.z; xb[3]=t3.w;
        xb[4]=t4.x; xb[5]=t4.y; xb[6]=t4.z; xb[7]=t4.w;
        xb[8]=t5.x; xb[9]=t5.y; xb[10]=t5.z; xb[11]=t5.w;
    }
    if (tid < NTRAIN) {
        const float4* xr = (const float4*)(X + tid*DIN);
        float4 t0 = xr[0], t1 = xr[1], t2 = xr[2];
        xi[0]=t0.x; xi[1]=t0.y; xi[2]=t0.z; xi[3]=t0.w;
        xi[4]=t1.x; xi[5]=t1.y; xi[6]=t1.z; xi[7]=t1.w;
        xi[8]=t2.x; xi[9]=t2.y; xi[10]=t2.z; xi[11]=t2.w;
    }

    // ---- stage 0: joint_var + per-dim scalars ----
    if (tid < 144) {
        int r = tid / 12, cl = tid % 12;
        float v;
        if (r < OBS && cl < OBS) {
            v = s_x[(b*OBS+r)*OBS + cl];
        } else if (r < OBS) {
            v = 0.f;
            #pragma unroll
            for (int k = 0; k < OBS; k++)
                v += s_x[(b*OBS+r)*OBS+k] * c_xu[(b*OBS+k)*ACT + (cl-OBS)];
        } else if (cl < OBS) {
            v = 0.f;
            #pragma unroll
            for (int k = 0; k < OBS; k++)
                v += s_x[(b*OBS+cl)*OBS+k] * c_xu[(b*OBS+k)*ACT + (r-OBS)];
        } else {
            v = s_u[(b*ACT+r-OBS)*ACT + (cl-OBS)];
        }
        jvs[tid] = v;
    } else if (tid >= 160 && tid < 172) {
        int d = tid - 160;
        mu[d] = (d < OBS) ? m_x[b*OBS+d] : m_u[b*ACT+d-OBS];
    } else if (tid >= 192 && tid < 204) {
        int d = tid - 192;
        if (isPair) {
            float la = ls[a*DIN+d]; la *= la;
            float lc = ls[c*DIN+d]; lc *= lc;
            float ia = 1.f/la, ic = 1.f/lc;
            float is = ia + ic;
            float L  = 1.f/is;
            sc_wsum[d] = 1.f/(la+lc);
            sc_iA[d] = L*ia;       // r_i = iA*x_i - mu
            sc_qc[d] = L*ic;       // q_j = qc*x_j
            sc_lam[d] = L;
            sc_isum[d] = is;
        } else {
            sc_iA[d] = 1.f / ls[e*DIN+d];   // inv lengthscale
        }
    }
    __syncthreads();

    // ---- stage 1: 12-lane shuffle Gauss-Jordan (wave 0, lanes 0..11) ----
    if (tid < DIN) {
        int r = tid;
        float row[12];
        if (isPair) {
            #pragma unroll
            for (int j = 0; j < 12; j++) row[j] = jvs[r*12+j];
            row[r] += sc_lam[r];                       // M = jv + diag(Lam)
        } else {
            float ir = sc_iA[r];
            #pragma unroll
            for (int j = 0; j < 12; j++) row[j] = ir * sc_iA[j] * jvs[r*12+j];
            row[r] += 1.f;                             // B = il*jv*il + I
        }
        float det = 1.f;
        #pragma unroll
        for (int k = 0; k < 12; k++) {
            float p = __shfl(row[k], k);
            float ip = 1.f / p;
            det *= p;
            float prow[12];
            #pragma unroll
            for (int j = 0; j < 12; j++) prow[j] = __shfl(row[j], k) * ip;
            if (r == k) {
                #pragma unroll
                for (int j = 0; j < 12; j++) row[j] = prow[j];
                row[k] = ip;
            } else {
                float f = row[k];
                #pragma unroll
                for (int j = 0; j < 12; j++) if (j != k) row[j] -= f * prow[j];
                row[k] = -f * ip;
            }
        }
        #pragma unroll
        for (int j = 0; j < 12; j++) Wl[r*12+j] = row[j];
        if (r == 0) {
            if (isPair) {
                float s = det;                          // det(R)=det(M)*prod(isum)
                #pragma unroll
                for (int d = 0; d < 12; d++) s *= sc_isum[d];
                s_cab = vars[a]*vars[c] / sqrtf(s);
            } else {
                s_cab = vars[e] / sqrtf(det);
            }
        }
    }
    __syncthreads();

    // ---- stage 2: sweep ----
    if (isPair) {
        bool diag = (a == c);
        // 2a: thread t<128 computes h-row (i=t) AND basej/wc (j=t), one Wl pass
        if (tid < NTRAIN) {
            int t = tid;
            float r[12], q[12]; float e1 = 0.f;
            #pragma unroll
            for (int d = 0; d < 12; d++) {
                r[d] = sc_iA[d]*xi[d] - mu[d];
                q[d] = sc_qc[d]*xi[d];
                e1 += sc_wsum[d]*xi[d]*xi[d];      // shared by i- and j-side
            }
            float hrow[16];
            float alpha = 0.f, bq = 0.f;
            #pragma unroll
            for (int d = 0; d < 12; d++) {
                float u = 0.f, uq = 0.f;
                #pragma unroll
                for (int cl = 0; cl < 12; cl++) {
                    float wv = Wl[d*12+cl];
                    u  += wv*r[cl];
                    uq += wv*q[cl];
                }
                alpha += r[d]*u;
                bq    += q[d]*uq;
                hrow[d] = sc_wsum[d]*xi[d] - u*sc_qc[d];   // folded cross term
            }
            hrow[12] = -0.5f*(e1 + alpha);                 // basei
            hrow[13] = beta[a*NTRAIN+t];                   // wav
            hrow[14] = 0.f; hrow[15] = 0.f;
            float4* hp = (float4*)&h[t][0];
            hp[0] = make_float4(hrow[0],hrow[1],hrow[2],hrow[3]);
            hp[1] = make_float4(hrow[4],hrow[5],hrow[6],hrow[7]);
            hp[2] = make_float4(hrow[8],hrow[9],hrow[10],hrow[11]);
            hp[3] = make_float4(hrow[12],hrow[13],hrow[14],hrow[15]);
            bw[t] = make_float2(-0.5f*(e1 + bq), beta[c*NTRAIN+t]);
        }
        __syncthreads();
        // 2b: sweep. lane owns j0=2l, 2l+1; wave w handles i = w + 8k.
        float4 bwv = ((const float4*)bw)[lane];   // {basej0, wc0, basej1, wc1}
        float basej0 = bwv.x, wc0 = bwv.y, basej1 = bwv.z, wc1 = bwv.w;
        float am0 = 0.f, am1 = 0.f, at0 = 0.f, at1 = 0.f;
        const float2* Kb = (const float2*)(invK + a*NTRAIN*NTRAIN);
        #pragma unroll 4
        for (int k = 0; k < 16; k++) {
            int i = w + 8*k;                         // wave-uniform -> LDS broadcast
            const float4* hp = (const float4*)&h[i][0];
            float4 h0 = hp[0], h1 = hp[1], h2 = hp[2];
            float2 h3 = *(const float2*)&h[i][12];   // {basei, wav}
            float sA0 = fmaf(h0.x,xa[0], fmaf(h0.y,xa[1], fmaf(h0.z,xa[2], h0.w*xa[3])));
            float sB0 = fmaf(h1.x,xa[4], fmaf(h1.y,xa[5], fmaf(h1.z,xa[6], h1.w*xa[7])));
            float sC0 = fmaf(h2.x,xa[8], fmaf(h2.y,xa[9], fmaf(h2.z,xa[10], h2.w*xa[11])));
            float sA1 = fmaf(h0.x,xb[0], fmaf(h0.y,xb[1], fmaf(h0.z,xb[2], h0.w*xb[3])));
            float sB1 = fmaf(h1.x,xb[4], fmaf(h1.y,xb[5], fmaf(h1.z,xb[6], h1.w*xb[7])));
            float sC1 = fmaf(h2.x,xb[8], fmaf(h2.y,xb[9], fmaf(h2.z,xb[10], h2.w*xb[11])));
            float e0  = __expf(sA0 + sB0 + sC0 + h3.x + basej0);
            float e1v = __expf(sA1 + sB1 + sC1 + h3.x + basej1);
            am0 = fmaf(h3.y, e0, am0);
            am1 = fmaf(h3.y, e1v, am1);
            if (diag) {
                float2 kv = Kb[i*64 + lane];          // Ka[i][2l], Ka[i][2l+1]
                at0 = fmaf(kv.x, e0, at0);
                at1 = fmaf(kv.y, e1v, at1);
            }
        }
        float accm = am0*wc0 + am1*wc1;
        float acct = at0 + at1;
        #pragma unroll
        for (int off = 32; off >= 1; off >>= 1) {
            accm += __shfl_xor(accm, off, 64);
            acct += __shfl_xor(acct, off, 64);
        }
        if (lane == 0) { red[w][0] = accm; red[w][1] = acct; }
        __syncthreads();
        if (tid == 0) {
            float m = 0.f, t = 0.f;
            #pragma unroll
            for (int v = 0; v < 8; v++) { m += red[v][0]; t += red[v][1]; }
            m *= s_cab; t *= s_cab;
            ws[WS_MN + b*64 + a*8 + c] = m;
            ws[WS_MN + b*64 + c*8 + a] = m;          // exact symmetry
            if (diag) ws[WS_TR + b*8 + a] = t;
        }
    } else {
        // gp predictive path (threads 0..127 active)
        float vals[13];
        #pragma unroll
        for (int v = 0; v < 13; v++) vals[v] = 0.f;
        if (tid < NTRAIN) {
            int n = tid;
            float iN[12];
            #pragma unroll
            for (int d = 0; d < 12; d++) iN[d] = (xi[d]-mu[d]) * sc_iA[d];
            float qq = 0.f; float tv[12];
            #pragma unroll
            for (int d = 0; d < 12; d++) {
                float u = 0.f;
                #pragma unroll
                for (int cl = 0; cl < 12; cl++) u += Wl[d*12+cl]*iN[cl];
                tv[d] = u; qq += iN[d]*u;
            }
            float lb = __expf(-0.5f*qq) * beta[e*NTRAIN+n];
            vals[0] = lb;
            #pragma unroll
            for (int d = 0; d < 12; d++) vals[1+d] = tv[d]*sc_iA[d]*lb;
        }
        #pragma unroll
        for (int v = 0; v < 13; v++)
            #pragma unroll
            for (int off = 32; off >= 1; off >>= 1) vals[v] += __shfl_xor(vals[v], off, 64);
        if (lane == 0) {
            #pragma unroll
            for (int v = 0; v < 13; v++) red[w][v] = vals[v];
        }
        __syncthreads();
        if (tid == 0) {
            float cn = s_cab;
            ws[WS_PM + b*OBS + e] = cn*(red[0][0]+red[1][0]);
            for (int d = 0; d < 12; d++)
                ws[WS_CC + (b*DIN+d)*OBS + e] = cn*(red[0][1+d]+red[1][1+d]);
        }
    }
}

// ---------------------------------------------------------------------------
// Epilogue. 8 blocks x 64 threads.
// ---------------------------------------------------------------------------
__global__ void k_final(const float* __restrict__ m_x, const float* __restrict__ s_x,
                        const float* __restrict__ c_xu, const float* __restrict__ vars,
                        const float* __restrict__ noises, const float* __restrict__ ws,
                        float* __restrict__ out) {
    int b = blockIdx.x, t = threadIdx.x;
    __shared__ float pm[OBS];
    __shared__ float sxs[64];
    const float* cc = ws + WS_CC + b*DIN*OBS;
    const float* mn = ws + WS_MN + b*64;
    const float* tr = ws + WS_TR + b*OBS;
    sxs[t] = s_x[b*64 + t];
    if (t < OBS) {
        float p = ws[WS_PM + b*OBS + t];
        pm[t] = p;
        out[b*OBS + t] = m_x[b*OBS + t] + p;        // m_out
    }
    __syncthreads();
    int r = t >> 3, cl = t & 7;
    float P = mn[r*8 + cl];
    if (r == cl) P += vars[r] - tr[r] + noises[r];
    P -= pm[r]*pm[cl];
    float cxf = 0.f, cxfT = 0.f;
    #pragma unroll
    for (int d = 0; d < 8; d++) {
        cxf  += sxs[r*8+d]  * cc[d*8+cl];
        cxfT += sxs[cl*8+d] * cc[d*8+r];
    }
    #pragma unroll
    for (int d = 0; d < 4; d++) {
        float jr = 0.f, jc = 0.f;
        #pragma unroll
        for (int k = 0; k < 8; k++) {
            float cx = c_xu[(b*OBS+k)*ACT + d];
            jr += sxs[r*8+k]  * cx;
            jc += sxs[cl*8+k] * cx;
        }
        cxf  += jr * cc[(8+d)*8 + cl];
        cxfT += jc * cc[(8+d)*8 + r];
    }
    float S = sxs[r*8+cl] + P + cxf + cxfT;
    if (r == cl) S += 1e-8f;
    out[64 + b*64 + t] = S;                          // s_out
}

// ---------------------------------------------------------------------------
extern "C" void kernel_launch(void* const* d_in, const int* in_sizes, int n_in,
                              void* d_out, int out_size, void* d_ws, size_t ws_size,
                              hipStream_t stream) {
    const float* m_x    = (const float*)d_in[0];
    const float* s_x    = (const float*)d_in[1];
    const float* m_u    = (const float*)d_in[2];
    const float* s_u    = (const float*)d_in[3];
    const float* c_xu   = (const float*)d_in[4];
    const float* X      = (const float*)d_in[5];
    const float* ls     = (const float*)d_in[6];
    const float* vars   = (const float*)d_in[7];
    const float* noises = (const float*)d_in[8];
    const float* invK   = (const float*)d_in[9];
    const float* beta   = (const float*)d_in[10];
    float* out = (float*)d_out;
    float* ws  = (float*)d_ws;

    k_fused<<<NTASK, THREADS, 0, stream>>>(m_x, s_x, m_u, s_u, c_xu, X, ls, vars,
                                           beta, invK, ws);
    k_final<<<BATCH, 64, 0, stream>>>(m_x, s_x, c_xu, vars, noises, ws, out);
}